// Round 3
// baseline (836.385 us; speedup 1.0000x reference)
//
#include <hip/hip_runtime.h>
#include <hip/hip_bf16.h>
#include <stdint.h>

typedef unsigned int u32;
typedef unsigned long long u64;

typedef short bf16x8 __attribute__((ext_vector_type(8)));
typedef float f32x4 __attribute__((ext_vector_type(4)));

// Problem constants: B=32, D=1024, N=65536, K=4096, H=8, hd=128
// Inputs are fp32 (per reference); internal GEMM compute uses bf16 MFMA.

__device__ __forceinline__ float bf2f(uint16_t x) {
    return __uint_as_float(((u32)x) << 16);
}
__device__ __forceinline__ uint16_t f2bf(float f) {
    // round-to-nearest-even bf16
    u32 u = __float_as_uint(f);
    u32 r = (u + 0x7FFF + ((u >> 16) & 1)) >> 16;
    return (uint16_t)r;
}

// ---------------- top-k: 64-bit sortable keys ----------------
// key = (descending-transformed fp32 bits << 32) | index
// ascending key sort == descending priority, ties broken by ascending index
// (matches jax.lax.top_k semantics)
__global__ void prio_keys_kernel(const float* __restrict__ prio, u64* __restrict__ keys) {
    int i = blockIdx.x * 256 + threadIdx.x;
    u32 fb = __float_as_uint(prio[i]);
    u32 s = (fb & 0x80000000u) ? ~fb : (fb | 0x80000000u); // ascending-sortable
    u32 ds = ~s;                                           // descending
    keys[i] = ((u64)ds << 32) | (u64)i;
}

__global__ __launch_bounds__(1024) void bitonic_local_full(u64* __restrict__ keys) {
    __shared__ u64 sh[2048];
    int t = threadIdx.x;
    int base = blockIdx.x * 2048;
    sh[t] = keys[base + t];
    sh[t + 1024] = keys[base + t + 1024];
    __syncthreads();
    for (int k = 2; k <= 2048; k <<= 1) {
        for (int j = k >> 1; j >= 1; j >>= 1) {
            int i1 = ((t & ~(j - 1)) << 1) | (t & (j - 1));
            int i2 = i1 | j;
            bool up = (((base + i1) & k) == 0);
            u64 a = sh[i1], b = sh[i2];
            if ((a > b) == up) { sh[i1] = b; sh[i2] = a; }
            __syncthreads();
        }
    }
    keys[base + t] = sh[t];
    keys[base + t + 1024] = sh[t + 1024];
}

__global__ void bitonic_global_kernel(u64* __restrict__ keys, int j, int k) {
    int t = blockIdx.x * 256 + threadIdx.x; // 32768 threads
    int i1 = ((t & ~(j - 1)) << 1) | (t & (j - 1));
    int i2 = i1 | j;
    bool up = ((i1 & k) == 0);
    u64 a = keys[i1], b = keys[i2];
    if ((a > b) == up) { keys[i1] = b; keys[i2] = a; }
}

__global__ __launch_bounds__(1024) void bitonic_local_tail(u64* __restrict__ keys, int k) {
    __shared__ u64 sh[2048];
    int t = threadIdx.x;
    int base = blockIdx.x * 2048;
    sh[t] = keys[base + t];
    sh[t + 1024] = keys[base + t + 1024];
    __syncthreads();
    for (int j = 1024; j >= 1; j >>= 1) {
        int i1 = ((t & ~(j - 1)) << 1) | (t & (j - 1));
        int i2 = i1 | j;
        bool up = (((base + i1) & k) == 0);
        u64 a = sh[i1], b = sh[i2];
        if ((a > b) == up) { sh[i1] = b; sh[i2] = a; }
        __syncthreads();
    }
    keys[base + t] = sh[t];
    keys[base + t + 1024] = sh[t + 1024];
}

__global__ void extract_idx_kernel(const u64* __restrict__ keys, int* __restrict__ idx) {
    int t = blockIdx.x * 256 + threadIdx.x; // 4096
    idx[t] = (int)(u32)(keys[t] & 0xFFFFFFFFull);
}

// ---------------- gather selected buffer rows, fp32 -> bf16 ----------------
__global__ __launch_bounds__(256) void gather_convert_kernel(const float* __restrict__ buffer,
                                                             const int* __restrict__ idx,
                                                             uint16_t* __restrict__ bsub) {
    int row = blockIdx.x;          // 4096 rows
    int c4 = threadIdx.x * 4;      // 256 threads x 4 floats = 1024
    const float* src = buffer + (size_t)idx[row] * 1024 + c4;
    float4 v = *(const float4*)src;
    ushort4 r;
    r.x = f2bf(v.x); r.y = f2bf(v.y); r.z = f2bf(v.z); r.w = f2bf(v.w);
    *(ushort4*)(bsub + (size_t)row * 1024 + c4) = r;
}

// ---------------- transpose Wk/Wv (fp32 -> bf16) for GEMM B-fragments ----------------
__global__ __launch_bounds__(256) void transpose_kernel(const float* __restrict__ Wk,
                                                        const float* __restrict__ Wv,
                                                        uint16_t* __restrict__ WkT,
                                                        uint16_t* __restrict__ WvT) {
    int tx = blockIdx.x, ty = blockIdx.y, m = blockIdx.z;
    const float* src = m ? Wv : Wk;
    uint16_t* dst = m ? WvT : WkT;
    __shared__ uint16_t tile[64][65];
    int t = threadIdx.x;
    for (int s = t; s < 4096; s += 256) {
        int r = s >> 6, c = s & 63;
        tile[r][c] = f2bf(src[(size_t)(ty * 64 + r) * 1024 + tx * 64 + c]);
    }
    __syncthreads();
    for (int s = t; s < 4096; s += 256) {
        int r = s >> 6, c = s & 63;
        dst[(size_t)(tx * 64 + r) * 1024 + ty * 64 + c] = tile[c][r];
    }
}

// ---------------- q projection: q = query @ Wq + bq (pure fp32) ----------------
__global__ __launch_bounds__(256) void qproj_kernel(const float* __restrict__ X,
                                                    const float* __restrict__ W,
                                                    const float* __restrict__ bias,
                                                    float* __restrict__ out) {
    int b = blockIdx.x, nc = blockIdx.y, t = threadIdx.x;
    __shared__ float xs[1024];
    for (int s = t; s < 1024; s += 256) xs[s] = X[b * 1024 + s];
    __syncthreads();
    int n = nc * 256 + t;
    float acc = bias[n];
#pragma unroll 4
    for (int k = 0; k < 1024; ++k) acc += xs[k] * W[(size_t)k * 1024 + n];
    out[b * 1024 + n] = acc;
}

// ---------------- gathered K/V projection GEMM (MFMA bf16), bf16 output ----------------
// C[m][n] = sum_k bsub[m][k] * W[k][n] + bias[n]; W given transposed: WT[n][k]
__global__ __launch_bounds__(256) void kv_gemm_kernel(const uint16_t* __restrict__ bsub,
                                                      const uint16_t* __restrict__ WT0,
                                                      const uint16_t* __restrict__ WT1,
                                                      const float* __restrict__ b0,
                                                      const float* __restrict__ b1,
                                                      uint16_t* __restrict__ out0,
                                                      uint16_t* __restrict__ out1) {
    const int nt = blockIdx.x, mt = blockIdx.y, mat = blockIdx.z;
    const uint16_t* WT = mat ? WT1 : WT0;
    const float* bias = mat ? b1 : b0;
    uint16_t* out = mat ? out1 : out0;

    __shared__ __align__(16) uint16_t As[128 * 64]; // [row m][8 chunks of 8 bf16], chunk xor-swizzled
    __shared__ __align__(16) uint16_t Bs[128 * 64]; // [row n][...]

    const int t = threadIdx.x;
    const int lane = t & 63;
    const int w = t >> 6;
    const int wm = (w >> 1) * 64, wn = (w & 1) * 64;
    const int q16 = lane >> 4;
    const int l15 = lane & 15;

    f32x4 acc[4][4];
#pragma unroll
    for (int i = 0; i < 4; i++)
#pragma unroll
        for (int j = 0; j < 4; j++) acc[i][j] = (f32x4){0.f, 0.f, 0.f, 0.f};

    const int sr = t >> 3; // 0..31
    const int sc = t & 7;  // logical 16B chunk

    for (int kk = 0; kk < 1024; kk += 64) {
#pragma unroll
        for (int p = 0; p < 4; ++p) {
            int r = p * 32 + sr;
            int pc = sc ^ (r & 7);
            uint4 va = *(const uint4*)(bsub + (size_t)(mt * 128 + r) * 1024 + kk + sc * 8);
            uint4 vb = *(const uint4*)(WT + (size_t)(nt * 128 + r) * 1024 + kk + sc * 8);
            *(uint4*)&As[r * 64 + pc * 8] = va;
            *(uint4*)&Bs[r * 64 + pc * 8] = vb;
        }
        __syncthreads();
#pragma unroll
        for (int f = 0; f < 2; ++f) {
            bf16x8 a[4], b[4];
#pragma unroll
            for (int i = 0; i < 4; ++i) {
                int m = wm + i * 16 + l15;
                int pc = (f * 4 + q16) ^ (m & 7);
                a[i] = *(const bf16x8*)&As[m * 64 + pc * 8];
                int n = wn + i * 16 + l15; // (n & 7) == (m & 7)
                b[i] = *(const bf16x8*)&Bs[n * 64 + pc * 8];
            }
#pragma unroll
            for (int i = 0; i < 4; ++i)
#pragma unroll
                for (int j = 0; j < 4; ++j)
                    acc[i][j] = __builtin_amdgcn_mfma_f32_16x16x32_bf16(a[i], b[j], acc[i][j], 0, 0, 0);
        }
        __syncthreads();
    }

    // epilogue: C/D layout col = lane&15, row = quad*4 + reg  [m89-verified]
#pragma unroll
    for (int j = 0; j < 4; ++j) {
        int n = nt * 128 + wn + j * 16 + l15;
        float bn = bias[n];
#pragma unroll
        for (int i = 0; i < 4; ++i) {
            int m0 = mt * 128 + wm + i * 16 + q16 * 4;
#pragma unroll
            for (int r = 0; r < 4; ++r)
                out[(size_t)(m0 + r) * 1024 + n] = f2bf(acc[i][j][r] + bn);
        }
    }
}

// ---------------- attention: scores = q . k * scale ----------------
__global__ __launch_bounds__(256) void scores_kernel(const float* __restrict__ q,
                                                     const uint16_t* __restrict__ ksub,
                                                     float* __restrict__ scores) {
    int h = blockIdx.x, kc = blockIdx.y, t = threadIdx.x;
    __shared__ float qsh[32][128];
    __shared__ float ksh[64][129];
    for (int s = t; s < 32 * 128; s += 256) {
        int b = s >> 7, d = s & 127;
        qsh[b][d] = q[b * 1024 + h * 128 + d];
    }
    for (int s = t; s < 64 * 128; s += 256) {
        int kl = s >> 7, d = s & 127;
        ksh[kl][d] = bf2f(ksub[(size_t)(kc * 64 + kl) * 1024 + h * 128 + d]);
    }
    __syncthreads();
    for (int s = t; s < 32 * 64; s += 256) {
        int b = s >> 6, kl = s & 63;
        float acc = 0.f;
#pragma unroll 4
        for (int d = 0; d < 128; ++d) acc += qsh[b][d] * ksh[kl][d];
        scores[(size_t)(b * 8 + h) * 4096 + kc * 64 + kl] = acc * 0.08838834764831845f;
    }
}

// ---------------- softmax over k (in place) ----------------
__global__ __launch_bounds__(256) void softmax_kernel(float* __restrict__ attn) {
    int row = blockIdx.x; // b*8 + h
    float* p = attn + (size_t)row * 4096;
    int t = threadIdx.x;
    __shared__ float red[4];
    __shared__ float red2[4];
    float m = -1e30f;
    for (int i = t; i < 4096; i += 256) m = fmaxf(m, p[i]);
#pragma unroll
    for (int o = 32; o >= 1; o >>= 1) m = fmaxf(m, __shfl_xor(m, o));
    if ((t & 63) == 0) red[t >> 6] = m;
    __syncthreads();
    m = fmaxf(fmaxf(red[0], red[1]), fmaxf(red[2], red[3]));
    float sum = 0.f;
    for (int i = t; i < 4096; i += 256) {
        float e = __expf(p[i] - m);
        p[i] = e;
        sum += e;
    }
#pragma unroll
    for (int o = 32; o >= 1; o >>= 1) sum += __shfl_xor(sum, o);
    if ((t & 63) == 0) red2[t >> 6] = sum;
    __syncthreads();
    sum = red2[0] + red2[1] + red2[2] + red2[3];
    float inv = 1.0f / sum;
    for (int i = t; i < 4096; i += 256) p[i] *= inv;
}

// ---------------- attn_avg = mean over heads -> fp32 out ----------------
__global__ void attn_avg_kernel(const float* __restrict__ attn, float* __restrict__ out) {
    int g = blockIdx.x * 256 + threadIdx.x; // 131072
    int b = g >> 12, k = g & 4095;
    float s = 0.f;
#pragma unroll
    for (int h = 0; h < 8; ++h) s += attn[(size_t)(b * 8 + h) * 4096 + k];
    out[g] = s * 0.125f;
}

// ---------------- ctx = attn @ v, one block per (b,h) ----------------
__global__ __launch_bounds__(256) void ctx_kernel(const float* __restrict__ attn,
                                                  const uint16_t* __restrict__ vsub,
                                                  float* __restrict__ ctx) {
    int b = blockIdx.x, h = blockIdx.y, t = threadIdx.x;
    int d = t & 127, half = t >> 7;
    __shared__ float ash[4096];
    __shared__ float red[128];
    const float* arow = attn + (size_t)(b * 8 + h) * 4096;
    for (int s = t; s < 4096; s += 256) ash[s] = arow[s];
    __syncthreads();
    float acc = 0.f;
    int k0 = half * 2048;
#pragma unroll 4
    for (int k = k0; k < k0 + 2048; ++k)
        acc += ash[k] * bf2f(vsub[(size_t)k * 1024 + h * 128 + d]);
    if (half) red[d] = acc;
    __syncthreads();
    if (!half) ctx[b * 1024 + h * 128 + d] = acc + red[d];
}

// ---------------- output projection: retrieved = ctx @ Wo + bo (pure fp32) ----------------
__global__ __launch_bounds__(256) void outproj_kernel(const float* __restrict__ ctx,
                                                      const float* __restrict__ W,
                                                      const float* __restrict__ bias,
                                                      float* __restrict__ out) {
    int b = blockIdx.x, nc = blockIdx.y, t = threadIdx.x;
    __shared__ float xs[1024];
    for (int s = t; s < 1024; s += 256) xs[s] = ctx[b * 1024 + s];
    __syncthreads();
    int n = nc * 256 + t;
    float acc = bias[n];
#pragma unroll 4
    for (int k = 0; k < 1024; ++k) acc += xs[k] * W[(size_t)k * 1024 + n];
    out[b * 1024 + n] = acc;
}

extern "C" void kernel_launch(void* const* d_in, const int* in_sizes, int n_in,
                              void* d_out, int out_size, void* d_ws, size_t ws_size,
                              hipStream_t stream) {
    const float* query  = (const float*)d_in[0];
    const float* buffer = (const float*)d_in[1];
    const float* prio   = (const float*)d_in[2];
    const float* Wq     = (const float*)d_in[3];
    const float* bq     = (const float*)d_in[4];
    const float* Wk     = (const float*)d_in[5];
    const float* bk     = (const float*)d_in[6];
    const float* Wv     = (const float*)d_in[7];
    const float* bv     = (const float*)d_in[8];
    const float* Wo     = (const float*)d_in[9];
    const float* bo     = (const float*)d_in[10];

    char* w = (char*)d_ws;
    auto alloc = [&](size_t bytes) {
        char* p = w;
        w += (bytes + 255) & ~(size_t)255;
        return p;
    };
    u64* keys      = (u64*)alloc((size_t)65536 * 8);            // 512 KB
    int* idx       = (int*)alloc((size_t)4096 * 4);             // 16 KB
    uint16_t* WkT  = (uint16_t*)alloc((size_t)1024 * 1024 * 2); // 2 MB
    uint16_t* WvT  = (uint16_t*)alloc((size_t)1024 * 1024 * 2); // 2 MB
    float* qp      = (float*)alloc((size_t)32 * 1024 * 4);      // 128 KB
    uint16_t* ksub = (uint16_t*)alloc((size_t)4096 * 1024 * 2); // 8 MB
    uint16_t* vsub = (uint16_t*)alloc((size_t)4096 * 1024 * 2); // 8 MB
    uint16_t* bsub = (uint16_t*)alloc((size_t)4096 * 1024 * 2); // 8 MB (reused as attn)
    float* ctx     = (float*)alloc((size_t)32 * 1024 * 4);      // 128 KB
    float* attn    = (float*)bsub; // 4 MB alias; bsub dead after kv_gemm

    float* out_retrieved = (float*)d_out;            // [32,1024]
    float* out_attnavg   = (float*)d_out + 32768;    // [32,4096]

    // 1. top-k selection (exact jax.lax.top_k semantics incl. tie order)
    prio_keys_kernel<<<256, 256, 0, stream>>>(prio, keys);
    bitonic_local_full<<<32, 1024, 0, stream>>>(keys);
    for (int k = 4096; k <= 65536; k <<= 1) {
        for (int j = k >> 1; j >= 2048; j >>= 1)
            bitonic_global_kernel<<<128, 256, 0, stream>>>(keys, j, k);
        bitonic_local_tail<<<32, 1024, 0, stream>>>(keys, k);
    }
    extract_idx_kernel<<<16, 256, 0, stream>>>(keys, idx);

    // 2. gather + convert, weight transposes, q projection
    gather_convert_kernel<<<4096, 256, 0, stream>>>(buffer, idx, bsub);
    transpose_kernel<<<dim3(16, 16, 2), 256, 0, stream>>>(Wk, Wv, WkT, WvT);
    qproj_kernel<<<dim3(32, 4), 256, 0, stream>>>(query, Wq, bq, qp);

    // 3. K/V projection GEMMs (MFMA bf16)
    kv_gemm_kernel<<<dim3(8, 32, 2), 256, 0, stream>>>(bsub, WkT, WvT, bk, bv, ksub, vsub);

    // 4. attention (attn aliases bsub — bsub dead after kv_gemm)
    scores_kernel<<<dim3(8, 64), 256, 0, stream>>>(qp, ksub, attn);
    softmax_kernel<<<256, 256, 0, stream>>>(attn);
    attn_avg_kernel<<<512, 256, 0, stream>>>(attn, out_attnavg);
    ctx_kernel<<<dim3(32, 8), 256, 0, stream>>>(attn, vsub, ctx);

    // 5. output projection
    outproj_kernel<<<dim3(32, 4), 256, 0, stream>>>(ctx, Wo, bo, out_retrieved);
}